// Round 12
// baseline (72.752 us; speedup 1.0000x reference)
//
#include <hip/hip_runtime.h>
#include <hip/hip_bf16.h>
#include <math.h>

// MoBoAligner forward — closed-form O(B*I*J) reformulation.
//
//   val[b,i,j]   = soft_ok ? (dot/256 - log(-log(u)))/temp : -1000
//   S_geq[b,i,k] = LSE_{j>=k} val[b,i,j]                (reverse cum-LSE)
//   g_i[p] = alpha_i[p] - S_geq[i][p+1]  (-inf if p==J-1 or !mel_mask[p])
//   C_i    = prefix cumLSE of g_i
//   alpha_{i+1}[j] = val[i][j-1] + C_i[j-2]    (masked j >= i+1)
//   w[i][q]  = exp(S_geq[i][q] + C_i[q-1]) + (J-q)*e^-10   ( = exp(delta) )
//   delta = log(w)  and  expanded = sum_i w * text   (fused kernelCD)
//
// kernelB: r11's segmented 2-scale scan body (passed, absmax 0.031) with a
// 4-buffer rotating prefetch: at body i, row i+3 is loaded into the buffer
// freed by body i-1 -> true 3-body (~1800 cy) latency slack, zero extra
// instructions vs 1-deep. Single-variable change to test the latency bound.
//
// Scale analysis (exact): true alpha <= 0, S_geq non-increasing and bimodal
// {normal >= ~-50, collapsed ~ -1443/temp}. gm is bimodal: head (<= ~50) or
// spike (~+1443/temp); collapsed-S positions form a SUFFIX. Prefix-LSE splits:
//   head prefix: log2(plain prefix-sum of 2^gm)              [exact]
//   tail prefix: Tfix + log2(prefix-sum of 2^(gm-Tfix))      [exact to ulp]
// Tfix = 1442.7/temp + 40 bounds all spikes; rows w/o spikes never use it.
// Mid-scale gm in (60,500): floor-dominated dead zone, clamped to 2^60.

#define B_ 4
#define I_ 64
#define J_ 512
#define D_ 256

#define NEGINF (-INFINITY)
#define LOG2E 1.4426950408889634f
#define SPIKE_THR 500.0f
#define MIDCLAMP 60.0f

// ---------------- Threefry-2x32-20, key = (0, 42) --------------------------
__device__ __forceinline__ void tf2x32(unsigned int x0, unsigned int x1,
                                       unsigned int& y0, unsigned int& y1) {
  const unsigned int k0 = 0u, k1 = 42u;
  const unsigned int k2 = k0 ^ k1 ^ 0x1BD11BDAu;
  x0 += k0; x1 += k1;
#define TFR(r) { x0 += x1; x1 = (x1 << r) | (x1 >> (32 - r)); x1 ^= x0; }
  TFR(13) TFR(15) TFR(26) TFR(6)   x0 += k1; x1 += k2 + 1u;
  TFR(17) TFR(29) TFR(16) TFR(24)  x0 += k2; x1 += k0 + 2u;
  TFR(13) TFR(15) TFR(26) TFR(6)   x0 += k0; x1 += k1 + 3u;
  TFR(17) TFR(29) TFR(16) TFR(24)  x0 += k1; x1 += k2 + 4u;
  TFR(13) TFR(15) TFR(26) TFR(6)   x0 += k2; x1 += k0 + 5u;
#undef TFR
  y0 = x0; y1 = x1;
}

__device__ __forceinline__ unsigned int rand_bits(unsigned int n) {
  unsigned int y0, y1;
  tf2x32(0u, n, y0, y1);
  return y0 ^ y1;
}

// log(-log(u)) with u = jax.random.uniform(key(42), ..., 1e-20, 1.0)[n]
__device__ __forceinline__ float gumbel_term(unsigned int n) {
  unsigned int bits = rand_bits(n);
  float f = __uint_as_float((bits >> 9) | 0x3f800000u) - 1.0f;  // [0,1)
  float u = fmaxf(f + 1e-20f, 1e-20f);
  return logf(-logf(u));
}

// ---------------- streaming logsumexp pairs (kernelA, natural log) ---------
struct MS { float m; float s; };

__device__ __forceinline__ MS ms_comb(MS a, MS b) {
  if (b.m == NEGINF) return a;
  if (a.m == NEGINF) return b;
  MS r;
  if (a.m >= b.m) { r.m = a.m; r.s = a.s + b.s * __expf(b.m - a.m); }
  else            { r.m = b.m; r.s = b.s + a.s * __expf(a.m - b.m); }
  return r;
}
__device__ __forceinline__ MS ms_add(MS a, float x) {
  if (x == NEGINF) return a;
  if (a.m == NEGINF) { MS r; r.m = x; r.s = 1.0f; return r; }
  MS r;
  if (a.m >= x) { r.m = a.m; r.s = a.s + __expf(x - a.m); }
  else          { r.m = x;   r.s = 1.0f + a.s * __expf(a.m - x); }
  return r;
}
__device__ __forceinline__ float ms_val(MS a) {
  if (a.m == NEGINF) return NEGINF;
  return a.m + __logf(a.s);
}

__device__ __forceinline__ MS wave_incl_scan(MS v, int lane) {
  #pragma unroll
  for (int off = 1; off < 64; off <<= 1) {
    float mo = __shfl_up(v.m, off, 64);
    float so = __shfl_up(v.s, off, 64);
    if (lane >= off) { MS o; o.m = mo; o.s = so; v = ms_comb(o, v); }
  }
  return v;
}

// ---------------- DPP helpers (kernelB) ------------------------------------
template<int CTRL, int RM, int BM, bool BC>
__device__ __forceinline__ float dppf(float oldv, float src) {
  return __int_as_float(__builtin_amdgcn_update_dpp(
      __float_as_int(oldv), __float_as_int(src), CTRL, RM, BM, BC));
}

// inclusive float add-scan over 64 lanes (invalid sources contribute 0)
__device__ __forceinline__ float wave_incl_add_f(float x) {
  x += dppf<0x111, 0xf, 0xf, false>(0.0f, x);  // row_shr:1
  x += dppf<0x112, 0xf, 0xf, false>(0.0f, x);  // row_shr:2
  x += dppf<0x114, 0xf, 0xf, false>(0.0f, x);  // row_shr:4
  x += dppf<0x118, 0xf, 0xf, false>(0.0f, x);  // row_shr:8
  x += dppf<0x142, 0xa, 0xf, false>(0.0f, x);  // row_bcast:15 -> rows 1,3
  x += dppf<0x143, 0xc, 0xf, false>(0.0f, x);  // row_bcast:31 -> rows 2,3
  return x;
}

// ---------------- mask helpers (bool-bytes vs int32 auto-detect) -----------
__device__ __forceinline__ bool mask_is_byte(const unsigned char* p) {
  const unsigned int* w = (const unsigned int*)p;
  unsigned int orbits = 0;
  #pragma unroll
  for (int k = 0; k < 16; k++) orbits |= w[k];
  return (orbits & 0xFFFFFF00u) != 0u;  // any high byte set -> byte layout
}
__device__ __forceinline__ int mask_get(const unsigned char* p, int idx, bool isbyte) {
  return isbyte ? (p[idx] != 0) : (((const int*)p)[idx] != 0);
}

// ============ Kernel A: val + S_geq per (b,i) row (stored in log2 domain) ==
__global__ __launch_bounds__(512) void kernelA(
    const float* __restrict__ text, const float* __restrict__ mel,
    const unsigned char* __restrict__ tmask, const unsigned char* __restrict__ mmask,
    const float* __restrict__ tratio,
    float* __restrict__ val2, float* __restrict__ sgeq2) {
  int bi = blockIdx.x;
  int b = bi >> 6, i = bi & 63;
  int tid = threadIdx.x;

  __shared__ float t_s[D_];
  __shared__ float v_s[J_];
  __shared__ int sh_ilen, sh_tok, sh_mbyte;

  if (tid == 0) {
    bool tbyte = mask_is_byte(tmask);
    int ilen = 0;
    for (int k = 0; k < I_; k++) ilen += mask_get(tmask, b * I_ + k, tbyte);
    sh_ilen = ilen;
    sh_tok = mask_get(tmask, b * I_ + i, tbyte);
    sh_mbyte = mask_is_byte(mmask) ? 1 : 0;
  }
  if (tid < D_) t_s[tid] = text[(size_t)(b * I_ + i) * D_ + tid];
  __syncthreads();

  int j = tid;  // 512 threads = one j each
  const float4* m4 = (const float4*)(mel + (size_t)(b * J_ + j) * D_);
  const float4* t4 = (const float4*)t_s;
  float4 acc; acc.x = acc.y = acc.z = acc.w = 0.0f;
  #pragma unroll 8
  for (int d4 = 0; d4 < D_ / 4; ++d4) {
    float4 a = m4[d4]; float4 t = t4[d4];
    acc.x += a.x * t.x; acc.y += a.y * t.y;
    acc.z += a.z * t.z; acc.w += a.w * t.w;
  }
  float dot = (acc.x + acc.y) + (acc.z + acc.w);

  float temp = 0.1f + 0.9f * tratio[0];
  float gum = gumbel_term((unsigned)((b * I_ + i) * J_ + j));
  float e = (dot * (1.0f / 256.0f) - gum) / temp;
  int mok = mask_get(mmask, b * J_ + j, sh_mbyte != 0);
  int hi = J_ - sh_ilen + i + 1;
  bool ok = (j >= i + 1) && (j <= hi) && mok && sh_tok;
  float v = ok ? e : -1000.0f;
  v_s[j] = v;                                   // natural log domain (internal)
  val2[(size_t)bi * J_ + j] = v * LOG2E;        // log2 domain for kernelB
  __syncthreads();

  // reverse cumulative LSE by wave 0: p = reversed index, lane l owns p=l*8+e
  if (tid < 64) {
    int l = tid;
    float xs[8];
    MS tot; tot.m = NEGINF; tot.s = 0.0f;
    #pragma unroll
    for (int e = 0; e < 8; e++) {
      int p = l * 8 + e;
      xs[e] = v_s[J_ - 1 - p];
      tot = ms_add(tot, xs[e]);
    }
    MS inc = wave_incl_scan(tot, l);
    MS ex; ex.m = __shfl_up(inc.m, 1, 64); ex.s = __shfl_up(inc.s, 1, 64);
    if (l == 0) { ex.m = NEGINF; ex.s = 0.0f; }
    MS run = ex;
    #pragma unroll
    for (int e = 0; e < 8; e++) {
      int p = l * 8 + e;
      run = ms_add(run, xs[e]);
      sgeq2[(size_t)bi * J_ + (J_ - 1 - p)] = ms_val(run) * LOG2E;
    }
  }
}

// ---------------- kernelB body: one DP row (identical math to r11) ---------
__device__ __forceinline__ void dp_body(
    int i, int p0, float4 Sa, float4 Sb, float4 Va, float4 Vb,
    float (&Am)[8], const float (&gokb)[8], const float (&floorc)[8],
    float Tfix, float* __restrict__ wb, int l) {
  float S[8] = {Sa.x, Sa.y, Sa.z, Sa.w, Sb.x, Sb.y, Sb.z, Sb.w};
  float V[8] = {Va.x, Va.y, Va.z, Va.w, Vb.x, Vb.y, Vb.z, Vb.w};

  // g[p] = alpha[p] - S[p+1] + mask; e=7 needs next lane's S[0]
  float nextS0 = dppf<0x130, 0xf, 0xf, false>(0.0f, S[0]);  // wave_shl:1
  float gm[8];
#pragma unroll
  for (int e = 0; e < 8; e++) {
    float sp1 = (e < 7) ? S[e + 1] : nextS0;
    gm[e] = (Am[e] - sp1) + gokb[e];   // -inf propagates, never NaN
  }

  // two-scale exp terms: head at 2^0 (clamped), tail (spikes) at 2^Tfix
  float h[8], t[8];
#pragma unroll
  for (int e = 0; e < 8; e++) {
    bool spk = gm[e] > SPIKE_THR;
    float arg = spk ? (gm[e] - Tfix) : fminf(gm[e], MIDCLAMP);
    float x = __builtin_amdgcn_exp2f(arg);   // gm=-inf -> 0
    h[e] = spk ? 0.0f : x;
    t[e] = spk ? x : 0.0f;
  }

  // in-lane inclusive prefixes (two independent chains, ILP)
  float hp[8], tp[8];
  hp[0] = h[0]; tp[0] = t[0];
#pragma unroll
  for (int e = 1; e < 8; e++) { hp[e] = hp[e - 1] + h[e]; tp[e] = tp[e - 1] + t[e]; }

  // wave add-scans of lane totals; exclusive via wave_shr:1 (lane0 -> 0)
  float hincl = wave_incl_add_f(hp[7]);
  float tincl = wave_incl_add_f(tp[7]);
  float hx = dppf<0x138, 0xf, 0xf, false>(0.0f, hincl);
  float tx = dppf<0x138, 0xf, 0xf, false>(0.0f, tincl);

  // prefix sums through p-1, then C1[e] = C[p-1] (true log2 value)
  float C1[8];
#pragma unroll
  for (int e = 0; e < 8; e++) {
    float pe1 = (e >= 1) ? hx + hp[e - 1] : hx;
    float tv1 = (e >= 1) ? tx + tp[e - 1] : tx;
    bool tl = tv1 > 0.0f;
    float sel = tl ? tv1 : pe1;
    C1[e] = (tl ? Tfix : 0.0f) + __log2f(sel);  // log2(0) = -inf (empty)
  }

  // w[q] = exp2(S[q] + C[q-1]) + floor   (delta = log(w) done in kernelCD)
  float wo[8];
#pragma unroll
  for (int e = 0; e < 8; e++)
    wo[e] = __builtin_amdgcn_exp2f(S[e] + C1[e]) + floorc[e];
  float4* w4 = (float4*)(wb + (size_t)i * J_);
  w4[l * 2]     = make_float4(wo[0], wo[1], wo[2], wo[3]);
  w4[l * 2 + 1] = make_float4(wo[4], wo[5], wo[6], wo[7]);

  // alpha_{i+1}[p] = V[p-1] + C[p-2] = V[p-1] + C1[p-1]; masked p >= i+1
  if (i < I_ - 1) {
    float prevV7  = dppf<0x138, 0xf, 0xf, false>(NEGINF, V[7]);
    float prevC17 = dppf<0x138, 0xf, 0xf, false>(NEGINF, C1[7]);
#pragma unroll
    for (int e = 0; e < 8; e++) {
      float vp = (e >= 1) ? V[e - 1]  : prevV7;
      float c2 = (e >= 1) ? C1[e - 1] : prevC17;
      Am[e] = ((p0 + e) >= i + 1) ? (vp + c2) : NEGINF;
    }
  }
}

// ============ Kernel B: DP over i — 4-buffer rotating prefetch =============
// 1 wave/batch, lane l owns p = l*8+e. At body i, row i+3 loads into the
// buffer freed by body i-1 -> 3-body latency slack, no copies.
__global__ __launch_bounds__(64) void kernelB(
    const float* __restrict__ val2, const float* __restrict__ sgeq2,
    const unsigned char* __restrict__ mmask, const float* __restrict__ tratio,
    float* __restrict__ wrow) {
  const int b = blockIdx.x;
  const int l = threadIdx.x;
  const int p0 = l << 3;

  const float temp = 0.1f + 0.9f * tratio[0];
  const float Tfix = 1442.695f / temp + 40.0f;  // >= max spike + 40

  const bool mbyte = mask_is_byte(mmask);
  float gokb[8], floorc[8], Am[8];
#pragma unroll
  for (int e = 0; e < 8; e++) {
    int p = p0 + e;
    bool ok = (p <= J_ - 2) && (mask_get(mmask, b * J_ + p, mbyte) != 0);
    gokb[e] = ok ? 0.0f : NEGINF;                           // additive mask
    floorc[e] = (float)(J_ - p) * 4.5399929762484854e-05f;  // (J-q)*e^-10
    Am[e] = (p == 0) ? 0.0f : NEGINF;
  }

  const float4* sb4 = (const float4*)(sgeq2 + (size_t)b * I_ * J_);
  const float4* vb4 = (const float4*)(val2  + (size_t)b * I_ * J_);
  float* wb = wrow + (size_t)b * I_ * J_;

  float4 SA0, SA1, VA0, VA1, SB0, SB1, VB0, VB1;
  float4 SC0, SC1, VC0, VC1, SD0, SD1, VD0, VD1;

#define LOADROW(X, row) { const int _ro = (row) * (J_ / 4) + (l << 1); \
    S##X##0 = sb4[_ro]; S##X##1 = sb4[_ro + 1]; \
    V##X##0 = vb4[_ro]; V##X##1 = vb4[_ro + 1]; }

  LOADROW(A, 0) LOADROW(B, 1) LOADROW(C, 2)

#define STEP(k, USE, LD) { \
    const int i = ii + k; \
    const int nr = (i + 3 < I_) ? i + 3 : I_ - 1; \
    LOADROW(LD, nr) \
    dp_body(i, p0, S##USE##0, S##USE##1, V##USE##0, V##USE##1, \
            Am, gokb, floorc, Tfix, wb, l); }

  for (int ii = 0; ii < I_; ii += 4) {
    STEP(0, A, D) STEP(1, B, A) STEP(2, C, B) STEP(3, D, C)
  }
#undef STEP
#undef LOADROW
}

// ============ Kernel CD: expanded (blocks < B*J) + delta (rest) ============
__global__ __launch_bounds__(256) void kernelCD(
    const float* __restrict__ wrow, const float* __restrict__ text,
    float* __restrict__ expanded, float* __restrict__ delta) {
  int blk = blockIdx.x;
  if (blk < B_ * J_) {
    int b = blk >> 9, j = blk & (J_ - 1);
    int d = threadIdx.x;
    __shared__ float w_s[I_];
    if (d < I_) w_s[d] = wrow[(size_t)(b * I_ + d) * J_ + j];
    __syncthreads();
    float acc = 0.0f;
    #pragma unroll 8
    for (int i = 0; i < I_; i++)
      acc += w_s[i] * text[(size_t)(b * I_ + i) * D_ + d];
    expanded[(size_t)(b * J_ + j) * D_ + d] = acc;
  } else {
    int n = (blk - B_ * J_) * 256 + threadIdx.x;  // B*I*J / 256 blocks
    delta[n] = __logf(wrow[n]);
  }
}

extern "C" void kernel_launch(void* const* d_in, const int* in_sizes, int n_in,
                              void* d_out, int out_size, void* d_ws, size_t ws_size,
                              hipStream_t stream) {
  (void)in_sizes; (void)n_in; (void)out_size; (void)ws_size;
  const float* text = (const float*)d_in[0];
  const float* mel  = (const float*)d_in[1];
  const unsigned char* tmask = (const unsigned char*)d_in[2];
  const unsigned char* mmask = (const unsigned char*)d_in[3];
  const float* tratio = (const float*)d_in[4];

  float* out = (float*)d_out;
  float* delta = out;                                  // B*I*J
  float* expanded = out + (size_t)B_ * I_ * J_;        // B*J*D
  float* val2  = (float*)d_ws;                         // B*I*J (log2 domain)
  float* sgeq2 = val2 + (size_t)B_ * I_ * J_;          // B*I*J (log2 domain)
  float* wrow  = sgeq2 + (size_t)B_ * I_ * J_;         // B*I*J

  kernelA<<<B_ * I_, 512, 0, stream>>>(text, mel, tmask, mmask, tratio, val2, sgeq2);
  kernelB<<<B_, 64, 0, stream>>>(val2, sgeq2, mmask, tratio, wrow);
  kernelCD<<<B_ * J_ + (B_ * I_ * J_) / 256, 256, 0, stream>>>(
      wrow, text, expanded, delta);
}